// Round 1
// baseline (2416.989 us; speedup 1.0000x reference)
//
#include <hip/hip_runtime.h>
#include <math.h>

#define CB 8
#define CC 256
#define CH 96
#define CWD 96
#define CL 144           // windows per image (12*12)
#define CN 1152          // total windows
#define CQ 64            // queries per window (8*8)
#define NHEADS 8
#define HD 32
#define HWSZ (CH*CWD)    // 9216
#define QSCALE 0.17677669529663687f   // 32^-0.5

// ---------------------------------------------------------------------------
// K1: pool partial GEMM.  part[s][row(window)][o] = sum over kk in slice s of
//     xw[row][kk] * pool_w[o][kk],  kk = c*64 + i*8 + j, slice = 32 channels.
// grid (18 rowtiles, 4 coltiles, 8 kslices), 256 thr, 64x64 tile, 4x4 micro.
// ---------------------------------------------------------------------------
__global__ __launch_bounds__(256) void k_pool(const float* __restrict__ x,
                                              const float* __restrict__ pw,
                                              float* __restrict__ part) {
  const int t  = threadIdx.x;
  const int tx = t & 15, ty = t >> 4;
  const int row0 = blockIdx.x * 64;
  const int col0 = blockIdx.y * 64;
  const int c0   = blockIdx.z * 32;

  __shared__ float As[16][68];
  __shared__ float Bs[16][68];

  const int kl = t & 15;     // staging inner index (ij within chunk)
  const int rA = t >> 4;     // staging row/col base (+16u)
  const int iA = kl >> 3, jA = kl & 7;

  int xbase[4]; int pwbase[4];
#pragma unroll
  for (int u = 0; u < 4; ++u) {
    int row = rA + 16 * u;
    int wdx = row0 + row;
    int b = wdx / CL, l = wdx - b * CL;
    int wh = l / 12, ww = l - wh * 12;
    xbase[u] = (b * CC) * HWSZ + (wh * 8) * CWD + ww * 8;   // + c*HWSZ + i*96 + j
    pwbase[u] = (col0 + row) * (CC * 64);                   // + c*64 + ij
  }

  float acc[4][4] = {};

  for (int cc = 0; cc < 32; ++cc) {
    const int c = c0 + cc;
    for (int ij0 = 0; ij0 < 64; ij0 += 16) {
      const int i0 = ij0 >> 3;
#pragma unroll
      for (int u = 0; u < 4; ++u) {
        As[kl][rA + 16 * u] = x[xbase[u] + c * HWSZ + (i0 + iA) * CWD + jA];
        Bs[kl][rA + 16 * u] = pw[pwbase[u] + c * 64 + ij0 + kl];
      }
      __syncthreads();
#pragma unroll
      for (int kk = 0; kk < 16; ++kk) {
        float4 a4 = *(const float4*)&As[kk][ty * 4];
        float4 b4 = *(const float4*)&Bs[kk][tx * 4];
        float av[4] = {a4.x, a4.y, a4.z, a4.w};
        float bv[4] = {b4.x, b4.y, b4.z, b4.w};
#pragma unroll
        for (int ri = 0; ri < 4; ++ri)
#pragma unroll
          for (int cj = 0; cj < 4; ++cj) acc[ri][cj] += av[ri] * bv[cj];
      }
      __syncthreads();
    }
  }

  float* outp = part + ((size_t)blockIdx.z * CN + row0) * CC + col0;
#pragma unroll
  for (int ri = 0; ri < 4; ++ri) {
    float4 v = make_float4(acc[ri][0], acc[ri][1], acc[ri][2], acc[ri][3]);
    *(float4*)&outp[(ty * 4 + ri) * CC + tx * 4] = v;
  }
}

// ---------------------------------------------------------------------------
// K1b: reduce 8 partials + bias -> pxr[1152][256]
// ---------------------------------------------------------------------------
__global__ __launch_bounds__(256) void k_poolred(const float* __restrict__ part,
                                                 const float* __restrict__ pbv,
                                                 float* __restrict__ pxr) {
  int base = (blockIdx.x * 256 + threadIdx.x) * 4;   // 288 blocks * 256 * 4 = 294912
  int m = base & 255;
  float4 s = *(const float4*)&pbv[m];
#pragma unroll
  for (int ss = 0; ss < 8; ++ss) {
    float4 p = *(const float4*)&part[(size_t)ss * (CN * CC) + base];
    s.x += p.x; s.y += p.y; s.z += p.z; s.w += p.w;
  }
  *(float4*)&pxr[base] = s;
}

// ---------------------------------------------------------------------------
// K2: kv GEMM [1152,256] @ Wkv^T -> scatter to k[b,h,l,d], v[b,h,l,d]
// grid (18 rowtiles, 8 coltiles)
// ---------------------------------------------------------------------------
__global__ __launch_bounds__(256) void k_kv(const float* __restrict__ pxr,
                                            const float* __restrict__ wkv,
                                            float* __restrict__ kbuf,
                                            float* __restrict__ vbuf) {
  const int t = threadIdx.x, tx = t & 15, ty = t >> 4;
  const int row0 = blockIdx.x * 64;
  const int col0 = blockIdx.y * 64;
  __shared__ float As[16][68];
  __shared__ float Bs[16][68];
  float acc[4][4] = {};
  const int ml = t & 15, rB = t >> 4;

  for (int mc = 0; mc < 16; ++mc) {
#pragma unroll
    for (int u = 0; u < 4; ++u) {
      int r = rB + 16 * u;
      As[ml][r] = pxr[(row0 + r) * CC + mc * 16 + ml];
      Bs[ml][r] = wkv[(col0 + r) * CC + mc * 16 + ml];
    }
    __syncthreads();
#pragma unroll
    for (int kk = 0; kk < 16; ++kk) {
      float4 a4 = *(const float4*)&As[kk][ty * 4];
      float4 b4 = *(const float4*)&Bs[kk][tx * 4];
      float av[4] = {a4.x, a4.y, a4.z, a4.w};
      float bv[4] = {b4.x, b4.y, b4.z, b4.w};
#pragma unroll
      for (int ri = 0; ri < 4; ++ri)
#pragma unroll
        for (int cj = 0; cj < 4; ++cj) acc[ri][cj] += av[ri] * bv[cj];
    }
    __syncthreads();
  }

#pragma unroll
  for (int ri = 0; ri < 4; ++ri) {
    int row = row0 + ty * 4 + ri;
    int b = row / CL, l = row - b * CL;
    int j = col0 + tx * 4;
    int d = j & 31, h = (j >> 5) & 7, tkv = j >> 8;
    float* dst = (tkv ? vbuf : kbuf) + ((size_t)(b * NHEADS + h) * CL + l) * HD + d;
    *(float4*)dst = make_float4(acc[ri][0], acc[ri][1], acc[ri][2], acc[ri][3]);
  }
}

// ---------------------------------------------------------------------------
// K3: q GEMM: q[row=(n,qq)][ch] = SCALE * sum_m xw[row][m]*Wq[ch][m],
//     written into d_out (flat layout identical to final attn-out slots).
// grid (1152 windows, 4 coltiles)
// ---------------------------------------------------------------------------
__global__ __launch_bounds__(256) void k_q(const float* __restrict__ x,
                                           const float* __restrict__ wq,
                                           float* __restrict__ qout) {
  const int t = threadIdx.x, tx = t & 15, ty = t >> 4;
  const int n = blockIdx.x;
  const int col0 = blockIdx.y * 64;
  const int b = n / CL, l = n - b * CL;
  const int wh = l / 12, ww = l - wh * 12;
  const size_t xwin = (size_t)(b * CC) * HWSZ + (wh * 8) * CWD + ww * 8;

  __shared__ float As[16][68];
  __shared__ float Bs[16][68];
  float acc[4][4] = {};

  const int rowA = t & 63;            // lane-major for spatial coalescing
  const int iA = rowA >> 3, jA = rowA & 7;
  const int klbase = t >> 6;          // + 4u
  const int mlB = t & 15, cB = t >> 4;

  for (int mc = 0; mc < 16; ++mc) {
#pragma unroll
    for (int u = 0; u < 4; ++u) {
      int kla = klbase + 4 * u;
      As[kla][rowA] = x[xwin + (size_t)(mc * 16 + kla) * HWSZ + iA * CWD + jA];
      int col = cB + 16 * u;
      Bs[mlB][col] = wq[(col0 + col) * CC + mc * 16 + mlB];
    }
    __syncthreads();
#pragma unroll
    for (int kk = 0; kk < 16; ++kk) {
      float4 a4 = *(const float4*)&As[kk][ty * 4];
      float4 b4 = *(const float4*)&Bs[kk][tx * 4];
      float av[4] = {a4.x, a4.y, a4.z, a4.w};
      float bv[4] = {b4.x, b4.y, b4.z, b4.w};
#pragma unroll
      for (int ri = 0; ri < 4; ++ri)
#pragma unroll
        for (int cj = 0; cj < 4; ++cj) acc[ri][cj] += av[ri] * bv[cj];
    }
    __syncthreads();
  }

  float* op = qout + (size_t)n * CQ * CC + col0;
#pragma unroll
  for (int ri = 0; ri < 4; ++ri) {
    float4 v = make_float4(acc[ri][0] * QSCALE, acc[ri][1] * QSCALE,
                           acc[ri][2] * QSCALE, acc[ri][3] * QSCALE);
    *(float4*)&op[(ty * 4 + ri) * CC + tx * 4] = v;
  }
}

// ---------------------------------------------------------------------------
// K4: attention, one block per window, in-place q -> attn-out in d_out.
//     Per head: stage q_h, k_h, v_h into LDS; scores -> softmax -> PV.
//     Thread map: qq = t>>2, lane-group lg = t&3 owns l = lg (mod 4).
// ---------------------------------------------------------------------------
__global__ __launch_bounds__(256) void k_attn(const float* __restrict__ kbuf,
                                              const float* __restrict__ vbuf,
                                              float* __restrict__ S) {
  const int n = blockIdx.x;
  const int bb = n & 7;
  const int t = threadIdx.x;
  const int qq = t >> 2, lg = t & 3;

  __shared__ float ks[CL][36];
  __shared__ float vs[CL][36];
  __shared__ float qs[CQ][36];

  float* Sn = S + (size_t)n * (CQ * CC);

  for (int h = 0; h < NHEADS; ++h) {
    __syncthreads();                 // prior head's compute done before restage
    const float* kh = kbuf + (size_t)(bb * NHEADS + h) * CL * HD;
    const float* vh = vbuf + (size_t)(bb * NHEADS + h) * CL * HD;
#pragma unroll
    for (int u = 0; u < 18; ++u) {
      int lin = t + 256 * u;
      int l = lin >> 5, d = lin & 31;
      ks[l][d] = kh[lin];
      vs[l][d] = vh[lin];
    }
#pragma unroll
    for (int u = 0; u < 8; ++u) {
      int lin = t + 256 * u;
      int d = lin & 31, qi = lin >> 5;
      qs[qi][d] = Sn[qi * CC + h * HD + d];
    }
    __syncthreads();

    float4 qv[8];
#pragma unroll
    for (int e = 0; e < 8; ++e) qv[e] = *(const float4*)&qs[qq][e * 4];

    float p[36];
#pragma unroll
    for (int il = 0; il < 36; ++il) {
      int l = il * 4 + lg;
      float s = 0.f;
#pragma unroll
      for (int e = 0; e < 8; ++e) {
        float4 k4 = *(const float4*)&ks[l][e * 4];
        s += qv[e].x * k4.x + qv[e].y * k4.y + qv[e].z * k4.z + qv[e].w * k4.w;
      }
      p[il] = s;
    }

    float mx = p[0];
#pragma unroll
    for (int il = 1; il < 36; ++il) mx = fmaxf(mx, p[il]);
    mx = fmaxf(mx, __shfl_xor(mx, 1, 4));
    mx = fmaxf(mx, __shfl_xor(mx, 2, 4));
    float sum = 0.f;
#pragma unroll
    for (int il = 0; il < 36; ++il) { p[il] = __expf(p[il] - mx); sum += p[il]; }
    sum += __shfl_xor(sum, 1, 4);
    sum += __shfl_xor(sum, 2, 4);
    const float inv = 1.0f / sum;

    float4 acc[8] = {};
#pragma unroll
    for (int il = 0; il < 36; ++il) {
      int l = il * 4 + lg;
      float w = p[il];
#pragma unroll
      for (int e = 0; e < 8; ++e) {
        float4 vv = *(const float4*)&vs[l][e * 4];
        acc[e].x += w * vv.x; acc[e].y += w * vv.y;
        acc[e].z += w * vv.z; acc[e].w += w * vv.w;
      }
    }
#pragma unroll
    for (int e = 0; e < 8; ++e) {
      acc[e].x += __shfl_xor(acc[e].x, 1, 4); acc[e].x += __shfl_xor(acc[e].x, 2, 4);
      acc[e].y += __shfl_xor(acc[e].y, 1, 4); acc[e].y += __shfl_xor(acc[e].y, 2, 4);
      acc[e].z += __shfl_xor(acc[e].z, 1, 4); acc[e].z += __shfl_xor(acc[e].z, 2, 4);
      acc[e].w += __shfl_xor(acc[e].w, 1, 4); acc[e].w += __shfl_xor(acc[e].w, 2, 4);
    }
#pragma unroll
    for (int e2 = 0; e2 < 2; ++e2) {
      int e = lg * 2 + e2;
      float4 o = acc[e];
      o.x *= inv; o.y *= inv; o.z *= inv; o.w *= inv;
      *(float4*)&Sn[qq * CC + h * HD + e * 4] = o;
    }
  }
}

// ---------------------------------------------------------------------------
// K5: depthwise 3x3 RPE (+bias) added into S. One block per (b,c) plane.
// ---------------------------------------------------------------------------
__global__ __launch_bounds__(256) void k_rpe(const float* __restrict__ x,
                                             const float* __restrict__ rw,
                                             const float* __restrict__ rb,
                                             float* __restrict__ S) {
  const int bc = blockIdx.x;
  const int c = bc & 255;
  const int t = threadIdx.x;
  __shared__ float xs[HWSZ];
  const float* xp = x + (size_t)bc * HWSZ;
  float* sp = S + (size_t)bc * HWSZ;
#pragma unroll
  for (int u = 0; u < 36; ++u) xs[t + 256 * u] = xp[t + 256 * u];
  float w9[9];
#pragma unroll
  for (int k = 0; k < 9; ++k) w9[k] = rw[c * 9 + k];
  const float bias = rb[c];
  __syncthreads();
  for (int u = 0; u < 36; ++u) {
    int idx = t + 256 * u;
    int hh = idx / 96, ww = idx - hh * 96;
    float s = bias;
#pragma unroll
    for (int di = 0; di < 3; ++di) {
      int h2 = hh + di - 1;
#pragma unroll
      for (int dj = 0; dj < 3; ++dj) {
        int w2 = ww + dj - 1;
        if ((unsigned)h2 < 96u && (unsigned)w2 < 96u)
          s += xs[h2 * 96 + w2] * w9[di * 3 + dj];
      }
    }
    sp[idx] += s;
  }
}

// ---------------------------------------------------------------------------
// K6: projection, in-place on d_out. Block owns 32 rows x all 256 outputs.
//     Stage rows to LDS, GEMM vs proj_w (chunked), write y back.
// ---------------------------------------------------------------------------
__global__ __launch_bounds__(256) void k_proj(const float* __restrict__ pwgt,
                                              const float* __restrict__ pb,
                                              float* __restrict__ S) {
  const int t = threadIdx.x, tx = t & 15, ty = t >> 4;
  const size_t row0 = (size_t)blockIdx.x * 32;
  __shared__ float Sl[32][260];
  __shared__ float Wl[256][36];
  float* Sp = S + row0 * CC;
#pragma unroll
  for (int u = 0; u < 32; ++u) {
    int lin = t + 256 * u;
    Sl[lin >> 8][lin & 255] = Sp[lin];
  }
  float acc[2][16] = {};
  const int mo = t & 31;
  const int ob = t >> 5;
  for (int mc = 0; mc < 8; ++mc) {
    __syncthreads();   // covers S staging (mc=0) and prior compute (mc>0)
#pragma unroll
    for (int u = 0; u < 32; ++u) {
      int o = ob + 8 * u;
      Wl[o][mo] = pwgt[o * CC + mc * 32 + mo];
    }
    __syncthreads();
#pragma unroll
    for (int mq = 0; mq < 8; ++mq) {
      int m = mq * 4;
      float4 s0 = *(const float4*)&Sl[ty * 2 + 0][mc * 32 + m];
      float4 s1 = *(const float4*)&Sl[ty * 2 + 1][mc * 32 + m];
#pragma unroll
      for (int oo = 0; oo < 16; ++oo) {
        int o = tx + 16 * oo;
        float4 w4 = *(const float4*)&Wl[o][m];
        acc[0][oo] += s0.x * w4.x + s0.y * w4.y + s0.z * w4.z + s0.w * w4.w;
        acc[1][oo] += s1.x * w4.x + s1.y * w4.y + s1.z * w4.z + s1.w * w4.w;
      }
    }
  }
#pragma unroll
  for (int rr = 0; rr < 2; ++rr) {
    int r = ty * 2 + rr;
#pragma unroll
    for (int oo = 0; oo < 16; ++oo) {
      int o = tx + 16 * oo;
      Sp[r * CC + o] = acc[rr][oo] + pb[o];
    }
  }
}

// ---------------------------------------------------------------------------
extern "C" void kernel_launch(void* const* d_in, const int* in_sizes, int n_in,
                              void* d_out, int out_size, void* d_ws, size_t ws_size,
                              hipStream_t stream) {
  const float* x    = (const float*)d_in[0];
  const float* wq   = (const float*)d_in[1];
  const float* wkv  = (const float*)d_in[2];
  const float* pw   = (const float*)d_in[3];
  const float* pbv  = (const float*)d_in[4];
  const float* rw   = (const float*)d_in[5];
  const float* rb   = (const float*)d_in[6];
  const float* pjw  = (const float*)d_in[7];
  const float* pjb  = (const float*)d_in[8];
  float* out = (float*)d_out;
  float* ws  = (float*)d_ws;

  float* part = ws;                               // 8*1152*256
  float* pxr  = part + 8 * CN * CC;               // 1152*256
  float* kbuf = pxr + CN * CC;                    // 8*8*144*32
  float* vbuf = kbuf + CB * NHEADS * CL * HD;     // 8*8*144*32

  k_pool   <<<dim3(18, 4, 8), 256, 0, stream>>>(x, pw, part);
  k_poolred<<<288,            256, 0, stream>>>(part, pbv, pxr);
  k_kv     <<<dim3(18, 8),    256, 0, stream>>>(pxr, wkv, kbuf, vbuf);
  k_q      <<<dim3(CN, 4),    256, 0, stream>>>(x, wq, out);
  k_attn   <<<CN,             256, 0, stream>>>(kbuf, vbuf, out);
  k_rpe    <<<CB * CC,        256, 0, stream>>>(x, rw, rb, out);
  k_proj   <<<2304,           256, 0, stream>>>(pjw, pjb, out);
}

// Round 2
// 1020.833 us; speedup vs baseline: 2.3677x; 2.3677x over previous
//
#include <hip/hip_runtime.h>
#include <math.h>

#define CB 8
#define CC 256
#define CH 96
#define CWD 96
#define CL 144           // windows per image (12*12)
#define CN 1152          // total windows
#define CQ 64            // queries per window (8*8)
#define NHEADS 8
#define HD 32
#define HWSZ (CH*CWD)    // 9216
#define QSCALE 0.17677669529663687f   // 32^-0.5

typedef __attribute__((ext_vector_type(4))) float  f32x4;
typedef __attribute__((ext_vector_type(4))) short  s16x4;
typedef __attribute__((ext_vector_type(8))) short  s16x8;
typedef __attribute__((ext_vector_type(8))) __bf16 bf16x8;

// round-to-nearest-even fp32 -> bf16 bits
static __device__ __forceinline__ short f2b(float f) {
  union { float f; unsigned u; } v; v.f = f;
  unsigned r = (v.u + 0x7fffu + ((v.u >> 16) & 1u)) >> 16;
  return (short)r;
}

// ---------------------------------------------------------------------------
// K1: pool partial GEMM.  part[s][row(window)][o] = sum over kk in slice s of
//     xw[row][kk] * pool_w[o][kk],  kk = c*64 + i*8 + j, slice = 32 channels.
// ---------------------------------------------------------------------------
__global__ __launch_bounds__(256) void k_pool(const float* __restrict__ x,
                                              const float* __restrict__ pw,
                                              float* __restrict__ part) {
  const int t  = threadIdx.x;
  const int tx = t & 15, ty = t >> 4;
  const int row0 = blockIdx.x * 64;
  const int col0 = blockIdx.y * 64;
  const int c0   = blockIdx.z * 32;

  __shared__ float As[16][68];
  __shared__ float Bs[16][68];

  const int kl = t & 15;
  const int rA = t >> 4;
  const int iA = kl >> 3, jA = kl & 7;

  int xbase[4]; int pwbase[4];
#pragma unroll
  for (int u = 0; u < 4; ++u) {
    int row = rA + 16 * u;
    int wdx = row0 + row;
    int b = wdx / CL, l = wdx - b * CL;
    int wh = l / 12, ww = l - wh * 12;
    xbase[u] = (b * CC) * HWSZ + (wh * 8) * CWD + ww * 8;
    pwbase[u] = (col0 + row) * (CC * 64);
  }

  float acc[4][4] = {};

  for (int cc = 0; cc < 32; ++cc) {
    const int c = c0 + cc;
    for (int ij0 = 0; ij0 < 64; ij0 += 16) {
      const int i0 = ij0 >> 3;
#pragma unroll
      for (int u = 0; u < 4; ++u) {
        As[kl][rA + 16 * u] = x[xbase[u] + c * HWSZ + (i0 + iA) * CWD + jA];
        Bs[kl][rA + 16 * u] = pw[pwbase[u] + c * 64 + ij0 + kl];
      }
      __syncthreads();
#pragma unroll
      for (int kk = 0; kk < 16; ++kk) {
        float4 a4 = *(const float4*)&As[kk][ty * 4];
        float4 b4 = *(const float4*)&Bs[kk][tx * 4];
        float av[4] = {a4.x, a4.y, a4.z, a4.w};
        float bv[4] = {b4.x, b4.y, b4.z, b4.w};
#pragma unroll
        for (int ri = 0; ri < 4; ++ri)
#pragma unroll
          for (int cj = 0; cj < 4; ++cj) acc[ri][cj] += av[ri] * bv[cj];
      }
      __syncthreads();
    }
  }

  float* outp = part + ((size_t)blockIdx.z * CN + row0) * CC + col0;
#pragma unroll
  for (int ri = 0; ri < 4; ++ri) {
    float4 v = make_float4(acc[ri][0], acc[ri][1], acc[ri][2], acc[ri][3]);
    *(float4*)&outp[(ty * 4 + ri) * CC + tx * 4] = v;
  }
}

// ---------------------------------------------------------------------------
// K1b: reduce 8 partials + bias -> pxr[1152][256]
// ---------------------------------------------------------------------------
__global__ __launch_bounds__(256) void k_poolred(const float* __restrict__ part,
                                                 const float* __restrict__ pbv,
                                                 float* __restrict__ pxr) {
  int base = (blockIdx.x * 256 + threadIdx.x) * 4;
  int m = base & 255;
  float4 s = *(const float4*)&pbv[m];
#pragma unroll
  for (int ss = 0; ss < 8; ++ss) {
    float4 p = *(const float4*)&part[(size_t)ss * (CN * CC) + base];
    s.x += p.x; s.y += p.y; s.z += p.z; s.w += p.w;
  }
  *(float4*)&pxr[base] = s;
}

// ---------------------------------------------------------------------------
// K2: kv GEMM [1152,256] @ Wkv^T -> scatter to k[b,h,l,d], v[b,h,l,d]
// ---------------------------------------------------------------------------
__global__ __launch_bounds__(256) void k_kv(const float* __restrict__ pxr,
                                            const float* __restrict__ wkv,
                                            float* __restrict__ kbuf,
                                            float* __restrict__ vbuf) {
  const int t = threadIdx.x, tx = t & 15, ty = t >> 4;
  const int row0 = blockIdx.x * 64;
  const int col0 = blockIdx.y * 64;
  __shared__ float As[16][68];
  __shared__ float Bs[16][68];
  float acc[4][4] = {};
  const int ml = t & 15, rB = t >> 4;

  for (int mc = 0; mc < 16; ++mc) {
#pragma unroll
    for (int u = 0; u < 4; ++u) {
      int r = rB + 16 * u;
      As[ml][r] = pxr[(row0 + r) * CC + mc * 16 + ml];
      Bs[ml][r] = wkv[(col0 + r) * CC + mc * 16 + ml];
    }
    __syncthreads();
#pragma unroll
    for (int kk = 0; kk < 16; ++kk) {
      float4 a4 = *(const float4*)&As[kk][ty * 4];
      float4 b4 = *(const float4*)&Bs[kk][tx * 4];
      float av[4] = {a4.x, a4.y, a4.z, a4.w};
      float bv[4] = {b4.x, b4.y, b4.z, b4.w};
#pragma unroll
      for (int ri = 0; ri < 4; ++ri)
#pragma unroll
        for (int cj = 0; cj < 4; ++cj) acc[ri][cj] += av[ri] * bv[cj];
    }
    __syncthreads();
  }

#pragma unroll
  for (int ri = 0; ri < 4; ++ri) {
    int row = row0 + ty * 4 + ri;
    int b = row / CL, l = row - b * CL;
    int j = col0 + tx * 4;
    int d = j & 31, h = (j >> 5) & 7, tkv = j >> 8;
    float* dst = (tkv ? vbuf : kbuf) + ((size_t)(b * NHEADS + h) * CL + l) * HD + d;
    *(float4*)dst = make_float4(acc[ri][0], acc[ri][1], acc[ri][2], acc[ri][3]);
  }
}

// ---------------------------------------------------------------------------
// K3: q GEMM into d_out (layout matches final attn-out slots)
// ---------------------------------------------------------------------------
__global__ __launch_bounds__(256) void k_q(const float* __restrict__ x,
                                           const float* __restrict__ wq,
                                           float* __restrict__ qout) {
  const int t = threadIdx.x, tx = t & 15, ty = t >> 4;
  const int n = blockIdx.x;
  const int col0 = blockIdx.y * 64;
  const int b = n / CL, l = n - b * CL;
  const int wh = l / 12, ww = l - wh * 12;
  const size_t xwin = (size_t)(b * CC) * HWSZ + (wh * 8) * CWD + ww * 8;

  __shared__ float As[16][68];
  __shared__ float Bs[16][68];
  float acc[4][4] = {};

  const int rowA = t & 63;
  const int iA = rowA >> 3, jA = rowA & 7;
  const int klbase = t >> 6;
  const int mlB = t & 15, cB = t >> 4;

  for (int mc = 0; mc < 16; ++mc) {
#pragma unroll
    for (int u = 0; u < 4; ++u) {
      int kla = klbase + 4 * u;
      As[kla][rowA] = x[xwin + (size_t)(mc * 16 + kla) * HWSZ + iA * CWD + jA];
      int col = cB + 16 * u;
      Bs[mlB][col] = wq[(col0 + col) * CC + mc * 16 + mlB];
    }
    __syncthreads();
#pragma unroll
    for (int kk = 0; kk < 16; ++kk) {
      float4 a4 = *(const float4*)&As[kk][ty * 4];
      float4 b4 = *(const float4*)&Bs[kk][tx * 4];
      float av[4] = {a4.x, a4.y, a4.z, a4.w};
      float bv[4] = {b4.x, b4.y, b4.z, b4.w};
#pragma unroll
      for (int ri = 0; ri < 4; ++ri)
#pragma unroll
        for (int cj = 0; cj < 4; ++cj) acc[ri][cj] += av[ri] * bv[cj];
    }
    __syncthreads();
  }

  float* op = qout + (size_t)n * CQ * CC + col0;
#pragma unroll
  for (int ri = 0; ri < 4; ++ri) {
    float4 v = make_float4(acc[ri][0] * QSCALE, acc[ri][1] * QSCALE,
                           acc[ri][2] * QSCALE, acc[ri][3] * QSCALE);
    *(float4*)&op[(ty * 4 + ri) * CC + tx * 4] = v;
  }
}

// ---------------------------------------------------------------------------
// K4 (v2, MFMA): one wave per (window, head) task. No LDS, no barriers.
//   S^T = K @ Q^T   via mfma_f32_16x16x32_bf16  (C/D: col=lane&15=q, row=quad*4+reg=l)
//   softmax over l  (in-register + shfl_xor 16/32 across quads)
//   O^T = V^T @ P^T via mfma_f32_16x16x16bf16_1k — P^T C-frag IS the B-frag
//   (k=quad*4+j matches row=quad*4+reg), so no transpose roundtrip.
// In-place on d_out: reads q slots of (n,h), overwrites same slots.
// ---------------------------------------------------------------------------
__global__ __launch_bounds__(256) void k_attn(const float* __restrict__ kbuf,
                                              const float* __restrict__ vbuf,
                                              float* __restrict__ S) {
  const int t = threadIdx.x;
  const int wv = t >> 6, lane = t & 63;
  const int col = lane & 15, quad = lane >> 4;
  const int task = blockIdx.x * 4 + wv;         // 9216 tasks
  const int n = task >> 3, h = task & 7;
  const int bb = n & 7;

  const float* kh = kbuf + (size_t)(bb * NHEADS + h) * CL * HD;
  const float* vh = vbuf + (size_t)(bb * NHEADS + h) * CL * HD;
  float* Sn = S + (size_t)n * (CQ * CC) + h * HD;

  // --- K A-frags for 16x16x32: A[m=l=lt*16+col][k=d=quad*8+j]
  bf16x8 ka[9];
#pragma unroll
  for (int lt = 0; lt < 9; ++lt) {
    const float* kr = kh + (lt * 16 + col) * HD + quad * 8;
    float4 lo = *(const float4*)kr;
    float4 hi = *(const float4*)(kr + 4);
    s16x8 p;
    p[0] = f2b(lo.x); p[1] = f2b(lo.y); p[2] = f2b(lo.z); p[3] = f2b(lo.w);
    p[4] = f2b(hi.x); p[5] = f2b(hi.y); p[6] = f2b(hi.z); p[7] = f2b(hi.w);
    ka[lt] = __builtin_bit_cast(bf16x8, p);
  }

  // --- V^T A-frags for 16x16x16: A[m=d=dt*16+col][k=l=lc*16+quad*4+j]
  s16x4 vt[2][9];
#pragma unroll
  for (int dt = 0; dt < 2; ++dt)
#pragma unroll
    for (int lc = 0; lc < 9; ++lc) {
      s16x4 p;
#pragma unroll
      for (int j = 0; j < 4; ++j)
        p[j] = f2b(vh[(lc * 16 + quad * 4 + j) * HD + dt * 16 + col]);
      vt[dt][lc] = p;
    }

  const f32x4 zero = {0.f, 0.f, 0.f, 0.f};

#pragma unroll
  for (int qt = 0; qt < 4; ++qt) {
    // Q^T B-frag: B[k=d=quad*8+j][n=q=qt*16+col]
    const float* qr = Sn + (size_t)(qt * 16 + col) * CC + quad * 8;
    float4 lo = *(const float4*)qr;
    float4 hi = *(const float4*)(qr + 4);
    s16x8 pq;
    pq[0] = f2b(lo.x); pq[1] = f2b(lo.y); pq[2] = f2b(lo.z); pq[3] = f2b(lo.w);
    pq[4] = f2b(hi.x); pq[5] = f2b(hi.y); pq[6] = f2b(hi.z); pq[7] = f2b(hi.w);
    bf16x8 qb = __builtin_bit_cast(bf16x8, pq);

    // scores S^T tile column: s[lt] covers l=lt*16+quad*4+reg, q=qt*16+col
    f32x4 s[9];
#pragma unroll
    for (int lt = 0; lt < 9; ++lt)
      s[lt] = __builtin_amdgcn_mfma_f32_16x16x32_bf16(ka[lt], qb, zero, 0, 0, 0);

    // softmax over l (rows): local regs + cross-quad shuffles
    float mx = s[0][0];
#pragma unroll
    for (int lt = 0; lt < 9; ++lt)
#pragma unroll
      for (int r = 0; r < 4; ++r) mx = fmaxf(mx, s[lt][r]);
    mx = fmaxf(mx, __shfl_xor(mx, 16, 64));
    mx = fmaxf(mx, __shfl_xor(mx, 32, 64));

    float sum = 0.f;
    s16x4 pb[9];
#pragma unroll
    for (int lt = 0; lt < 9; ++lt) {
      s16x4 pp;
#pragma unroll
      for (int r = 0; r < 4; ++r) {
        float e = __expf(s[lt][r] - mx);
        sum += e;
        pp[r] = f2b(e);
      }
      pb[lt] = pp;
    }
    sum += __shfl_xor(sum, 16, 64);
    sum += __shfl_xor(sum, 32, 64);
    const float inv = 1.0f / sum;

    // O^T = V^T @ P^T, accumulate over 9 l-chunks
    f32x4 o0 = zero, o1 = zero;
#pragma unroll
    for (int lc = 0; lc < 9; ++lc) {
      o0 = __builtin_amdgcn_mfma_f32_16x16x16bf16_1k(vt[0][lc], pb[lc], o0, 0, 0, 0);
      o1 = __builtin_amdgcn_mfma_f32_16x16x16bf16_1k(vt[1][lc], pb[lc], o1, 0, 0, 0);
    }

    // write O: q = qt*16+col (lane), d = dt*16 + quad*4 + reg (float4)
    float* orow = Sn + (size_t)(qt * 16 + col) * CC;
    *(float4*)&orow[quad * 4] =
        make_float4(o0[0] * inv, o0[1] * inv, o0[2] * inv, o0[3] * inv);
    *(float4*)&orow[16 + quad * 4] =
        make_float4(o1[0] * inv, o1[1] * inv, o1[2] * inv, o1[3] * inv);
  }
}

// ---------------------------------------------------------------------------
// K5: depthwise 3x3 RPE (+bias) added into S. One block per (b,c) plane.
// ---------------------------------------------------------------------------
__global__ __launch_bounds__(256) void k_rpe(const float* __restrict__ x,
                                             const float* __restrict__ rw,
                                             const float* __restrict__ rb,
                                             float* __restrict__ S) {
  const int bc = blockIdx.x;
  const int c = bc & 255;
  const int t = threadIdx.x;
  __shared__ float xs[HWSZ];
  const float* xp = x + (size_t)bc * HWSZ;
  float* sp = S + (size_t)bc * HWSZ;
#pragma unroll
  for (int u = 0; u < 36; ++u) xs[t + 256 * u] = xp[t + 256 * u];
  float w9[9];
#pragma unroll
  for (int k = 0; k < 9; ++k) w9[k] = rw[c * 9 + k];
  const float bias = rb[c];
  __syncthreads();
  for (int u = 0; u < 36; ++u) {
    int idx = t + 256 * u;
    int hh = idx / 96, ww = idx - hh * 96;
    float s = bias;
#pragma unroll
    for (int di = 0; di < 3; ++di) {
      int h2 = hh + di - 1;
#pragma unroll
      for (int dj = 0; dj < 3; ++dj) {
        int w2 = ww + dj - 1;
        if ((unsigned)h2 < 96u && (unsigned)w2 < 96u)
          s += xs[h2 * 96 + w2] * w9[di * 3 + dj];
      }
    }
    sp[idx] += s;
  }
}

// ---------------------------------------------------------------------------
// K6: projection, in-place on d_out.
// ---------------------------------------------------------------------------
__global__ __launch_bounds__(256) void k_proj(const float* __restrict__ pwgt,
                                              const float* __restrict__ pb,
                                              float* __restrict__ S) {
  const int t = threadIdx.x, tx = t & 15, ty = t >> 4;
  const size_t row0 = (size_t)blockIdx.x * 32;
  __shared__ float Sl[32][260];
  __shared__ float Wl[256][36];
  float* Sp = S + row0 * CC;
#pragma unroll
  for (int u = 0; u < 32; ++u) {
    int lin = t + 256 * u;
    Sl[lin >> 8][lin & 255] = Sp[lin];
  }
  float acc[2][16] = {};
  const int mo = t & 31;
  const int ob = t >> 5;
  for (int mc = 0; mc < 8; ++mc) {
    __syncthreads();
#pragma unroll
    for (int u = 0; u < 32; ++u) {
      int o = ob + 8 * u;
      Wl[o][mo] = pwgt[o * CC + mc * 32 + mo];
    }
    __syncthreads();
#pragma unroll
    for (int mq = 0; mq < 8; ++mq) {
      int m = mq * 4;
      float4 s0 = *(const float4*)&Sl[ty * 2 + 0][mc * 32 + m];
      float4 s1 = *(const float4*)&Sl[ty * 2 + 1][mc * 32 + m];
#pragma unroll
      for (int oo = 0; oo < 16; ++oo) {
        int o = tx + 16 * oo;
        float4 w4 = *(const float4*)&Wl[o][m];
        acc[0][oo] += s0.x * w4.x + s0.y * w4.y + s0.z * w4.z + s0.w * w4.w;
        acc[1][oo] += s1.x * w4.x + s1.y * w4.y + s1.z * w4.z + s1.w * w4.w;
      }
    }
  }
#pragma unroll
  for (int rr = 0; rr < 2; ++rr) {
    int r = ty * 2 + rr;
#pragma unroll
    for (int oo = 0; oo < 16; ++oo) {
      int o = tx + 16 * oo;
      Sp[r * CC + o] = acc[rr][oo] + pb[o];
    }
  }
}

// ---------------------------------------------------------------------------
extern "C" void kernel_launch(void* const* d_in, const int* in_sizes, int n_in,
                              void* d_out, int out_size, void* d_ws, size_t ws_size,
                              hipStream_t stream) {
  const float* x    = (const float*)d_in[0];
  const float* wq   = (const float*)d_in[1];
  const float* wkv  = (const float*)d_in[2];
  const float* pw   = (const float*)d_in[3];
  const float* pbv  = (const float*)d_in[4];
  const float* rw   = (const float*)d_in[5];
  const float* rb   = (const float*)d_in[6];
  const float* pjw  = (const float*)d_in[7];
  const float* pjb  = (const float*)d_in[8];
  float* out = (float*)d_out;
  float* ws  = (float*)d_ws;

  float* part = ws;                               // 8*1152*256
  float* pxr  = part + 8 * CN * CC;               // 1152*256
  float* kbuf = pxr + CN * CC;                    // 8*8*144*32
  float* vbuf = kbuf + CB * NHEADS * CL * HD;     // 8*8*144*32

  k_pool   <<<dim3(18, 4, 8), 256, 0, stream>>>(x, pw, part);
  k_poolred<<<288,            256, 0, stream>>>(part, pbv, pxr);
  k_kv     <<<dim3(18, 8),    256, 0, stream>>>(pxr, wkv, kbuf, vbuf);
  k_q      <<<dim3(CN, 4),    256, 0, stream>>>(x, wq, out);
  k_attn   <<<2304,           256, 0, stream>>>(kbuf, vbuf, out);
  k_rpe    <<<CB * CC,        256, 0, stream>>>(x, rw, rb, out);
  k_proj   <<<2304,           256, 0, stream>>>(pjw, pjb, out);
}

// Round 3
// 512.871 us; speedup vs baseline: 4.7127x; 1.9904x over previous
//
#include <hip/hip_runtime.h>
#include <math.h>

#define CB 8
#define CC 256
#define CH 96
#define CWD 96
#define CL 144           // windows per image (12*12)
#define CN 1152          // total windows
#define CQ 64            // queries per window (8*8)
#define NHEADS 8
#define HD 32
#define HWSZ (CH*CWD)    // 9216
#define QSCALE 0.17677669529663687f   // 32^-0.5

typedef __attribute__((ext_vector_type(4))) float  f32x4;
typedef __attribute__((ext_vector_type(4))) short  s16x4;
typedef __attribute__((ext_vector_type(8))) short  s16x8;
typedef __attribute__((ext_vector_type(8))) __bf16 bf16x8;

// round-to-nearest-even fp32 -> bf16 bits
static __device__ __forceinline__ short f2b(float f) {
  union { float f; unsigned u; } v; v.f = f;
  unsigned r = (v.u + 0x7fffu + ((v.u >> 16) & 1u)) >> 16;
  return (short)r;
}

static __device__ __forceinline__ bf16x8 pack8(float4 lo, float4 hi) {
  s16x8 p;
  p[0] = f2b(lo.x); p[1] = f2b(lo.y); p[2] = f2b(lo.z); p[3] = f2b(lo.w);
  p[4] = f2b(hi.x); p[5] = f2b(hi.y); p[6] = f2b(hi.z); p[7] = f2b(hi.w);
  return __builtin_bit_cast(bf16x8, p);
}

// ---------------------------------------------------------------------------
// K0: fp32 -> bf16 bulk convert (8 elems / thread)
// ---------------------------------------------------------------------------
__global__ __launch_bounds__(256) void k_cvt(const float* __restrict__ s,
                                             short* __restrict__ d, int n8) {
  int i = blockIdx.x * 256 + threadIdx.x;
  if (i >= n8) return;
  const float4* p = (const float4*)s + (size_t)i * 2;
  float4 a = p[0], b = p[1];
  s16x8 o;
  o[0] = f2b(a.x); o[1] = f2b(a.y); o[2] = f2b(a.z); o[3] = f2b(a.w);
  o[4] = f2b(b.x); o[5] = f2b(b.y); o[6] = f2b(b.z); o[7] = f2b(b.w);
  *(s16x8*)(d + (size_t)i * 8) = o;
}

// ---------------------------------------------------------------------------
// K1 (MFMA): pool partial GEMM, split-K x8.
//   part[ks][wdx][o] = sum_{k in slice} xw[wdx][k] * pw[o][k]
//   A-frag straight from x (8 consecutive k = one 8-wide window row).
//   B-frag from bf16 pool_w (k-contiguous). grid (18 Mblk, 2 Nblk, 8 Kslice).
//   Wave: 16 rows x 128 cols (8 o-tiles).
// ---------------------------------------------------------------------------
__global__ __launch_bounds__(256) void k_pool(const float* __restrict__ x,
                                              const short* __restrict__ pwb,
                                              float* __restrict__ part) {
  const int t = threadIdx.x, lane = t & 63, w = t >> 6;
  const int col = lane & 15, quad = lane >> 4;
  const int mb = blockIdx.x, nh = blockIdx.y, ks = blockIdx.z;
  const int wdx = mb * 64 + w * 16 + col;
  const int b = wdx / CL, l = wdx - b * CL;
  const int wh = l / 12, ww = l - wh * 12;
  const size_t xbase = (size_t)b * CC * HWSZ + wh * 8 * CWD + ww * 8;
  const int col0 = nh * 128;

  f32x4 acc[8] = {};

  for (int kc = 0; kc < 64; ++kc) {
    const int c = ks * 32 + (kc >> 1);
    const int i = (kc & 1) * 4 + quad;
    const float* ap = x + xbase + (size_t)c * HWSZ + i * CWD;
    float4 lo = *(const float4*)ap, hi = *(const float4*)(ap + 4);
    bf16x8 af = pack8(lo, hi);
    const int kg = ks * 2048 + kc * 32 + quad * 8;
#pragma unroll
    for (int ot = 0; ot < 8; ++ot) {
      s16x8 rb = *(const s16x8*)(pwb + (size_t)(col0 + ot * 16 + col) * 16384 + kg);
      acc[ot] = __builtin_amdgcn_mfma_f32_16x16x32_bf16(
          af, __builtin_bit_cast(bf16x8, rb), acc[ot], 0, 0, 0);
    }
  }

  float* pp = part + ((size_t)ks * CN + mb * 64 + w * 16) * CC + col0;
#pragma unroll
  for (int ot = 0; ot < 8; ++ot)
#pragma unroll
    for (int r = 0; r < 4; ++r)
      pp[(quad * 4 + r) * CC + ot * 16 + col] = acc[ot][r];
}

// ---------------------------------------------------------------------------
// K1b: reduce 8 partials + bias -> pxr[1152][256]
// ---------------------------------------------------------------------------
__global__ __launch_bounds__(256) void k_poolred(const float* __restrict__ part,
                                                 const float* __restrict__ pbv,
                                                 float* __restrict__ pxr) {
  int base = (blockIdx.x * 256 + threadIdx.x) * 4;
  int m = base & 255;
  float4 s = *(const float4*)&pbv[m];
#pragma unroll
  for (int ss = 0; ss < 8; ++ss) {
    float4 p = *(const float4*)&part[(size_t)ss * (CN * CC) + base];
    s.x += p.x; s.y += p.y; s.z += p.z; s.w += p.w;
  }
  *(float4*)&pxr[base] = s;
}

// ---------------------------------------------------------------------------
// K2: kv GEMM [1152,256] @ Wkv^T -> scatter to k[b,h,l,d], v[b,h,l,d]  (fp32)
// ---------------------------------------------------------------------------
__global__ __launch_bounds__(256) void k_kv(const float* __restrict__ pxr,
                                            const float* __restrict__ wkv,
                                            float* __restrict__ kbuf,
                                            float* __restrict__ vbuf) {
  const int t = threadIdx.x, tx = t & 15, ty = t >> 4;
  const int row0 = blockIdx.x * 64;
  const int col0 = blockIdx.y * 64;
  __shared__ float As[16][68];
  __shared__ float Bs[16][68];
  float acc[4][4] = {};
  const int ml = t & 15, rB = t >> 4;

  for (int mc = 0; mc < 16; ++mc) {
#pragma unroll
    for (int u = 0; u < 4; ++u) {
      int r = rB + 16 * u;
      As[ml][r] = pxr[(row0 + r) * CC + mc * 16 + ml];
      Bs[ml][r] = wkv[(col0 + r) * CC + mc * 16 + ml];
    }
    __syncthreads();
#pragma unroll
    for (int kk = 0; kk < 16; ++kk) {
      float4 a4 = *(const float4*)&As[kk][ty * 4];
      float4 b4 = *(const float4*)&Bs[kk][tx * 4];
      float av[4] = {a4.x, a4.y, a4.z, a4.w};
      float bv[4] = {b4.x, b4.y, b4.z, b4.w};
#pragma unroll
      for (int ri = 0; ri < 4; ++ri)
#pragma unroll
        for (int cj = 0; cj < 4; ++cj) acc[ri][cj] += av[ri] * bv[cj];
    }
    __syncthreads();
  }

#pragma unroll
  for (int ri = 0; ri < 4; ++ri) {
    int row = row0 + ty * 4 + ri;
    int b = row / CL, l = row - b * CL;
    int j = col0 + tx * 4;
    int d = j & 31, h = (j >> 5) & 7, tkv = j >> 8;
    float* dst = (tkv ? vbuf : kbuf) + ((size_t)(b * NHEADS + h) * CL + l) * HD + d;
    *(float4*)dst = make_float4(acc[ri][0], acc[ri][1], acc[ri][2], acc[ri][3]);
  }
}

// ---------------------------------------------------------------------------
// K3 (MFMA): q^T = Wq * xw^T per window; C-layout store transposes back into
//   d_out q slots (row = n*64+qq, col = ch) with float4 stores.
//   xw staged to LDS as bf16 [qq][c] (full 64x256 window, one barrier).
// ---------------------------------------------------------------------------
__global__ __launch_bounds__(256) void k_q(const float* __restrict__ x,
                                           const short* __restrict__ wqb,
                                           float* __restrict__ qout) {
  const int t = threadIdx.x, lane = t & 63, w = t >> 6;
  const int col = lane & 15, quad = lane >> 4;
  const int n = blockIdx.x;
  const int b = n / CL, l = n - b * CL;
  const int wh = l / 12, ww = l - wh * 12;
  const size_t xwin = (size_t)b * CC * HWSZ + wh * 8 * CWD + ww * 8;

  __shared__ short xq[64][264];
  {
    const int ci = t & 31, ii = t >> 5;
#pragma unroll
    for (int u = 0; u < 8; ++u) {
      const float* ap = x + xwin + (size_t)(ci + 32 * u) * HWSZ + ii * CWD;
      float4 lo = *(const float4*)ap, hi = *(const float4*)(ap + 4);
      float vals[8] = {lo.x, lo.y, lo.z, lo.w, hi.x, hi.y, hi.z, hi.w};
#pragma unroll
      for (int j = 0; j < 8; ++j) xq[ii * 8 + j][ci + 32 * u] = f2b(vals[j]);
    }
  }
  __syncthreads();

  f32x4 acc[4][4] = {};
  for (int kc = 0; kc < 8; ++kc) {
    bf16x8 af[4];
#pragma unroll
    for (int cht = 0; cht < 4; ++cht) {
      s16x8 r = *(const s16x8*)(wqb + (size_t)(w * 64 + cht * 16 + col) * CC + kc * 32 + quad * 8);
      af[cht] = __builtin_bit_cast(bf16x8, r);
    }
#pragma unroll
    for (int qt = 0; qt < 4; ++qt) {
      s16x8 rb = *(const s16x8*)&xq[qt * 16 + col][kc * 32 + quad * 8];
      bf16x8 bfv = __builtin_bit_cast(bf16x8, rb);
#pragma unroll
      for (int cht = 0; cht < 4; ++cht)
        acc[cht][qt] = __builtin_amdgcn_mfma_f32_16x16x32_bf16(af[cht], bfv, acc[cht][qt], 0, 0, 0);
    }
  }

  float* op = qout + (size_t)n * CQ * CC;
#pragma unroll
  for (int qt = 0; qt < 4; ++qt)
#pragma unroll
    for (int cht = 0; cht < 4; ++cht) {
      f32x4 v = acc[cht][qt];
      *(float4*)&op[(qt * 16 + col) * CC + w * 64 + cht * 16 + quad * 4] =
          make_float4(v[0] * QSCALE, v[1] * QSCALE, v[2] * QSCALE, v[3] * QSCALE);
    }
}

// ---------------------------------------------------------------------------
// K4 (MFMA): attention, one wave per (window, head). In-place q -> out.
// ---------------------------------------------------------------------------
__global__ __launch_bounds__(256) void k_attn(const float* __restrict__ kbuf,
                                              const float* __restrict__ vbuf,
                                              float* __restrict__ S) {
  const int t = threadIdx.x;
  const int wv = t >> 6, lane = t & 63;
  const int col = lane & 15, quad = lane >> 4;
  const int task = blockIdx.x * 4 + wv;         // 9216 tasks
  const int n = task >> 3, h = task & 7;
  const int bb = n & 7;

  const float* kh = kbuf + (size_t)(bb * NHEADS + h) * CL * HD;
  const float* vh = vbuf + (size_t)(bb * NHEADS + h) * CL * HD;
  float* Sn = S + (size_t)n * (CQ * CC) + h * HD;

  bf16x8 ka[9];
#pragma unroll
  for (int lt = 0; lt < 9; ++lt) {
    const float* kr = kh + (lt * 16 + col) * HD + quad * 8;
    ka[lt] = pack8(*(const float4*)kr, *(const float4*)(kr + 4));
  }

  s16x4 vt[2][9];
#pragma unroll
  for (int dt = 0; dt < 2; ++dt)
#pragma unroll
    for (int lc = 0; lc < 9; ++lc) {
      s16x4 p;
#pragma unroll
      for (int j = 0; j < 4; ++j)
        p[j] = f2b(vh[(lc * 16 + quad * 4 + j) * HD + dt * 16 + col]);
      vt[dt][lc] = p;
    }

  const f32x4 zero = {0.f, 0.f, 0.f, 0.f};

#pragma unroll
  for (int qt = 0; qt < 4; ++qt) {
    const float* qr = Sn + (size_t)(qt * 16 + col) * CC + quad * 8;
    bf16x8 qb = pack8(*(const float4*)qr, *(const float4*)(qr + 4));

    f32x4 s[9];
#pragma unroll
    for (int lt = 0; lt < 9; ++lt)
      s[lt] = __builtin_amdgcn_mfma_f32_16x16x32_bf16(ka[lt], qb, zero, 0, 0, 0);

    float mx = s[0][0];
#pragma unroll
    for (int lt = 0; lt < 9; ++lt)
#pragma unroll
      for (int r = 0; r < 4; ++r) mx = fmaxf(mx, s[lt][r]);
    mx = fmaxf(mx, __shfl_xor(mx, 16, 64));
    mx = fmaxf(mx, __shfl_xor(mx, 32, 64));

    float sum = 0.f;
    s16x4 pb[9];
#pragma unroll
    for (int lt = 0; lt < 9; ++lt) {
      s16x4 pp;
#pragma unroll
      for (int r = 0; r < 4; ++r) {
        float e = __expf(s[lt][r] - mx);
        sum += e;
        pp[r] = f2b(e);
      }
      pb[lt] = pp;
    }
    sum += __shfl_xor(sum, 16, 64);
    sum += __shfl_xor(sum, 32, 64);
    const float inv = 1.0f / sum;

    f32x4 o0 = zero, o1 = zero;
#pragma unroll
    for (int lc = 0; lc < 9; ++lc) {
      o0 = __builtin_amdgcn_mfma_f32_16x16x16bf16_1k(vt[0][lc], pb[lc], o0, 0, 0, 0);
      o1 = __builtin_amdgcn_mfma_f32_16x16x16bf16_1k(vt[1][lc], pb[lc], o1, 0, 0, 0);
    }

    float* orow = Sn + (size_t)(qt * 16 + col) * CC;
    *(float4*)&orow[quad * 4] =
        make_float4(o0[0] * inv, o0[1] * inv, o0[2] * inv, o0[3] * inv);
    *(float4*)&orow[16 + quad * 4] =
        make_float4(o1[0] * inv, o1[1] * inv, o1[2] * inv, o1[3] * inv);
  }
}

// ---------------------------------------------------------------------------
// K5: depthwise 3x3 RPE (+bias) added into S. One block per (b,c) plane.
// ---------------------------------------------------------------------------
__global__ __launch_bounds__(256) void k_rpe(const float* __restrict__ x,
                                             const float* __restrict__ rw,
                                             const float* __restrict__ rb,
                                             float* __restrict__ S) {
  const int bc = blockIdx.x;
  const int c = bc & 255;
  const int t = threadIdx.x;
  __shared__ float xs[HWSZ];
  const float* xp = x + (size_t)bc * HWSZ;
  float* sp = S + (size_t)bc * HWSZ;
#pragma unroll
  for (int u = 0; u < 36; ++u) xs[t + 256 * u] = xp[t + 256 * u];
  float w9[9];
#pragma unroll
  for (int k = 0; k < 9; ++k) w9[k] = rw[c * 9 + k];
  const float bias = rb[c];
  __syncthreads();
  for (int u = 0; u < 36; ++u) {
    int idx = t + 256 * u;
    int hh = idx / 96, ww = idx - hh * 96;
    float s = bias;
#pragma unroll
    for (int di = 0; di < 3; ++di) {
      int h2 = hh + di - 1;
#pragma unroll
      for (int dj = 0; dj < 3; ++dj) {
        int w2 = ww + dj - 1;
        if ((unsigned)h2 < 96u && (unsigned)w2 < 96u)
          s += xs[h2 * 96 + w2] * w9[di * 3 + dj];
      }
    }
    sp[idx] += s;
  }
}

// ---------------------------------------------------------------------------
// K6 (MFMA): projection, in-place on d_out. Block = 64 rows x 256 cols.
//   S tile staged once to LDS as bf16 (shared conversion), B from bf16 proj_w.
// ---------------------------------------------------------------------------
__global__ __launch_bounds__(256) void k_proj(const short* __restrict__ pjwb,
                                              const float* __restrict__ pjb,
                                              float* __restrict__ S) {
  const int t = threadIdx.x, lane = t & 63, w = t >> 6;
  const int col = lane & 15, quad = lane >> 4;
  const size_t row0 = (size_t)blockIdx.x * 64;

  __shared__ short Sl[64][264];
  const float* Sp = S + row0 * CC;
#pragma unroll
  for (int u = 0; u < 16; ++u) {
    int idx = u * 1024 + t * 4;
    float4 v = *(const float4*)&Sp[idx];
    s16x4 pv;
    pv[0] = f2b(v.x); pv[1] = f2b(v.y); pv[2] = f2b(v.z); pv[3] = f2b(v.w);
    *(s16x4*)&Sl[idx >> 8][idx & 255] = pv;
  }
  __syncthreads();

  f32x4 acc[4][4] = {};
  for (int kc = 0; kc < 8; ++kc) {
    bf16x8 bfr[4];
#pragma unroll
    for (int ot = 0; ot < 4; ++ot) {
      s16x8 r = *(const s16x8*)(pjwb + (size_t)(w * 64 + ot * 16 + col) * CC + kc * 32 + quad * 8);
      bfr[ot] = __builtin_bit_cast(bf16x8, r);
    }
#pragma unroll
    for (int mt = 0; mt < 4; ++mt) {
      s16x8 ra = *(const s16x8*)&Sl[mt * 16 + col][kc * 32 + quad * 8];
      bf16x8 af = __builtin_bit_cast(bf16x8, ra);
#pragma unroll
      for (int ot = 0; ot < 4; ++ot)
        acc[mt][ot] = __builtin_amdgcn_mfma_f32_16x16x32_bf16(af, bfr[ot], acc[mt][ot], 0, 0, 0);
    }
  }

  float bias[4];
#pragma unroll
  for (int ot = 0; ot < 4; ++ot) bias[ot] = pjb[w * 64 + ot * 16 + col];
  float* Sw = S + row0 * CC;
#pragma unroll
  for (int mt = 0; mt < 4; ++mt)
#pragma unroll
    for (int ot = 0; ot < 4; ++ot)
#pragma unroll
      for (int r = 0; r < 4; ++r)
        Sw[(mt * 16 + quad * 4 + r) * CC + w * 64 + ot * 16 + col] = acc[mt][ot][r] + bias[ot];
}

// ---------------------------------------------------------------------------
extern "C" void kernel_launch(void* const* d_in, const int* in_sizes, int n_in,
                              void* d_out, int out_size, void* d_ws, size_t ws_size,
                              hipStream_t stream) {
  const float* x    = (const float*)d_in[0];
  const float* wq   = (const float*)d_in[1];
  const float* wkv  = (const float*)d_in[2];
  const float* pw   = (const float*)d_in[3];
  const float* pbv  = (const float*)d_in[4];
  const float* rw   = (const float*)d_in[5];
  const float* rb   = (const float*)d_in[6];
  const float* pjw  = (const float*)d_in[7];
  const float* pjb  = (const float*)d_in[8];
  float* out = (float*)d_out;
  float* ws  = (float*)d_ws;

  float* part = ws;                               // 8*1152*256 f
  float* pxr  = part + 8 * CN * CC;               // 1152*256 f
  float* kbuf = pxr + CN * CC;                    // 8*8*144*32 f
  float* vbuf = kbuf + CB * NHEADS * CL * HD;     // 8*8*144*32 f
  short* pwb  = (short*)(vbuf + CB * NHEADS * CL * HD);  // 4194304 sh
  short* wqb  = pwb + 4194304;                    // 65536 sh
  short* pjwb = wqb + 65536;                      // 65536 sh

  k_cvt    <<<2048, 256, 0, stream>>>(pw,  pwb,  524288);
  k_cvt    <<<32,   256, 0, stream>>>(wq,  wqb,  8192);
  k_cvt    <<<32,   256, 0, stream>>>(pjw, pjwb, 8192);

  k_pool   <<<dim3(18, 2, 8), 256, 0, stream>>>(x, pwb, part);
  k_poolred<<<288,            256, 0, stream>>>(part, pbv, pxr);
  k_kv     <<<dim3(18, 8),    256, 0, stream>>>(pxr, wkv, kbuf, vbuf);
  k_q      <<<CN,             256, 0, stream>>>(x, wqb, out);
  k_attn   <<<2304,           256, 0, stream>>>(kbuf, vbuf, out);
  k_rpe    <<<CB * CC,        256, 0, stream>>>(x, rw, rb, out);
  k_proj   <<<1152,           256, 0, stream>>>(pjwb, pjb, out);
}

// Round 4
// 441.968 us; speedup vs baseline: 5.4687x; 1.1604x over previous
//
#include <hip/hip_runtime.h>
#include <math.h>

#define CB 8
#define CC 256
#define CH 96
#define CWD 96
#define CL 144           // windows per image (12*12)
#define CN 1152          // total windows
#define CQ 64            // queries per window (8*8)
#define NHEADS 8
#define HD 32
#define HWSZ (CH*CWD)    // 9216
#define QSCALE 0.17677669529663687f   // 32^-0.5
#define NSLICE 32        // pool split-K slices (8 channels each)

typedef __attribute__((ext_vector_type(4))) float  f32x4;
typedef __attribute__((ext_vector_type(4))) short  s16x4;
typedef __attribute__((ext_vector_type(8))) short  s16x8;
typedef __attribute__((ext_vector_type(8))) __bf16 bf16x8;

// round-to-nearest-even fp32 -> bf16 bits
static __device__ __forceinline__ short f2b(float f) {
  union { float f; unsigned u; } v; v.f = f;
  unsigned r = (v.u + 0x7fffu + ((v.u >> 16) & 1u)) >> 16;
  return (short)r;
}

static __device__ __forceinline__ bf16x8 pack8(float4 lo, float4 hi) {
  s16x8 p;
  p[0] = f2b(lo.x); p[1] = f2b(lo.y); p[2] = f2b(lo.z); p[3] = f2b(lo.w);
  p[4] = f2b(hi.x); p[5] = f2b(hi.y); p[6] = f2b(hi.z); p[7] = f2b(hi.w);
  return __builtin_bit_cast(bf16x8, p);
}

// ---------------------------------------------------------------------------
// K0: fp32 -> bf16 bulk convert (8 elems / thread)
// ---------------------------------------------------------------------------
__global__ __launch_bounds__(256) void k_cvt(const float* __restrict__ s,
                                             short* __restrict__ d, int n8) {
  int i = blockIdx.x * 256 + threadIdx.x;
  if (i >= n8) return;
  const float4* p = (const float4*)s + (size_t)i * 2;
  float4 a = p[0], b = p[1];
  s16x8 o;
  o[0] = f2b(a.x); o[1] = f2b(a.y); o[2] = f2b(a.z); o[3] = f2b(a.w);
  o[4] = f2b(b.x); o[5] = f2b(b.y); o[6] = f2b(b.z); o[7] = f2b(b.w);
  *(s16x8*)(d + (size_t)i * 8) = o;
}

// ---------------------------------------------------------------------------
// K0b: pool_w -> bf16, K-blocked fragment-native layout.
//   pw2[((ks*16 + kc)*256 + o)*32 + kk] = bf16( pw[o][kglob] ),
//   kglob = ks*512 + kc*32 + kk  (k = c*64 + i*8 + j ordering, unchanged).
//   A wave's B-frag load becomes one contiguous 1 KB block.
// ---------------------------------------------------------------------------
__global__ __launch_bounds__(256) void k_cvtp(const float* __restrict__ pw,
                                              short* __restrict__ pw2) {
  int g = blockIdx.x * 256 + threadIdx.x;      // 524288 groups of 8
  int kk8 = (g & 3) * 8;
  int o   = (g >> 2) & 255;
  int kc  = (g >> 10) & 15;
  int ks  = g >> 14;
  int kglob = ks * 512 + kc * 32 + kk8;
  const float* src = pw + (size_t)o * 16384 + kglob;  // 8 contiguous floats (ij-run)
  float4 a = *(const float4*)src, b = *(const float4*)(src + 4);
  s16x8 oo;
  oo[0] = f2b(a.x); oo[1] = f2b(a.y); oo[2] = f2b(a.z); oo[3] = f2b(a.w);
  oo[4] = f2b(b.x); oo[5] = f2b(b.y); oo[6] = f2b(b.z); oo[7] = f2b(b.w);
  *(s16x8*)(pw2 + (size_t)g * 8) = oo;
}

// ---------------------------------------------------------------------------
// K1 (MFMA v3): pool partial GEMM, split-K x32 (8 channels per slice).
//   grid (18 Mblk, 2 Nblk, 32 Kslice) = 1152 blocks (~4.5/CU).
//   A-frag direct from x (contiguous 32B/lane across adjacent windows).
//   B-frag from pw2: contiguous 1 KB per load (coalesced).
//   Partials land in d_out (unused until k_q overwrites it).
// ---------------------------------------------------------------------------
__global__ __launch_bounds__(256) void k_pool(const float* __restrict__ x,
                                              const short* __restrict__ pw2,
                                              float* __restrict__ part) {
  const int t = threadIdx.x, lane = t & 63, w = t >> 6;
  const int col = lane & 15, quad = lane >> 4;
  const int mb = blockIdx.x, nh = blockIdx.y, ks = blockIdx.z;
  const int wdx = mb * 64 + w * 16 + col;
  const int b = wdx / CL, l = wdx - b * CL;
  const int wh = l / 12, ww = l - wh * 12;
  const size_t xbase = (size_t)b * CC * HWSZ + wh * 8 * CWD + ww * 8;

  f32x4 acc[8] = {};

#pragma unroll 4
  for (int kc = 0; kc < 16; ++kc) {
    const int c = ks * 8 + (kc >> 1);
    const int i = (kc & 1) * 4 + quad;
    const float* ap = x + xbase + (size_t)c * HWSZ + i * CWD;
    bf16x8 af = pack8(*(const float4*)ap, *(const float4*)(ap + 4));
    const short* bk = pw2 + ((size_t)(ks * 16 + kc) * 256 + nh * 128) * 32;
#pragma unroll
    for (int ot = 0; ot < 8; ++ot) {
      s16x8 rb = *(const s16x8*)(bk + (ot * 16 + col) * 32 + quad * 8);
      acc[ot] = __builtin_amdgcn_mfma_f32_16x16x32_bf16(
          af, __builtin_bit_cast(bf16x8, rb), acc[ot], 0, 0, 0);
    }
  }

  float* pp = part + ((size_t)ks * CN + mb * 64 + w * 16) * CC + nh * 128;
#pragma unroll
  for (int ot = 0; ot < 8; ++ot)
#pragma unroll
    for (int r = 0; r < 4; ++r)
      pp[(quad * 4 + r) * CC + ot * 16 + col] = acc[ot][r];
}

// ---------------------------------------------------------------------------
// K1b: reduce 32 partials + bias -> pxr[1152][256]
// ---------------------------------------------------------------------------
__global__ __launch_bounds__(256) void k_poolred(const float* __restrict__ part,
                                                 const float* __restrict__ pbv,
                                                 float* __restrict__ pxr) {
  int base = (blockIdx.x * 256 + threadIdx.x) * 4;
  int m = base & 255;
  float4 s = *(const float4*)&pbv[m];
#pragma unroll
  for (int ss = 0; ss < NSLICE; ++ss) {
    float4 p = *(const float4*)&part[(size_t)ss * (CN * CC) + base];
    s.x += p.x; s.y += p.y; s.z += p.z; s.w += p.w;
  }
  *(float4*)&pxr[base] = s;
}

// ---------------------------------------------------------------------------
// K2: kv GEMM [1152,256] @ Wkv^T -> scatter to k[b,h,l,d], v[b,h,l,d]  (fp32)
// ---------------------------------------------------------------------------
__global__ __launch_bounds__(256) void k_kv(const float* __restrict__ pxr,
                                            const float* __restrict__ wkv,
                                            float* __restrict__ kbuf,
                                            float* __restrict__ vbuf) {
  const int t = threadIdx.x, tx = t & 15, ty = t >> 4;
  const int row0 = blockIdx.x * 64;
  const int col0 = blockIdx.y * 64;
  __shared__ float As[16][68];
  __shared__ float Bs[16][68];
  float acc[4][4] = {};
  const int ml = t & 15, rB = t >> 4;

  for (int mc = 0; mc < 16; ++mc) {
#pragma unroll
    for (int u = 0; u < 4; ++u) {
      int r = rB + 16 * u;
      As[ml][r] = pxr[(row0 + r) * CC + mc * 16 + ml];
      Bs[ml][r] = wkv[(col0 + r) * CC + mc * 16 + ml];
    }
    __syncthreads();
#pragma unroll
    for (int kk = 0; kk < 16; ++kk) {
      float4 a4 = *(const float4*)&As[kk][ty * 4];
      float4 b4 = *(const float4*)&Bs[kk][tx * 4];
      float av[4] = {a4.x, a4.y, a4.z, a4.w};
      float bv[4] = {b4.x, b4.y, b4.z, b4.w};
#pragma unroll
      for (int ri = 0; ri < 4; ++ri)
#pragma unroll
        for (int cj = 0; cj < 4; ++cj) acc[ri][cj] += av[ri] * bv[cj];
    }
    __syncthreads();
  }

#pragma unroll
  for (int ri = 0; ri < 4; ++ri) {
    int row = row0 + ty * 4 + ri;
    int b = row / CL, l = row - b * CL;
    int j = col0 + tx * 4;
    int d = j & 31, h = (j >> 5) & 7, tkv = j >> 8;
    float* dst = (tkv ? vbuf : kbuf) + ((size_t)(b * NHEADS + h) * CL + l) * HD + d;
    *(float4*)dst = make_float4(acc[ri][0], acc[ri][1], acc[ri][2], acc[ri][3]);
  }
}

// ---------------------------------------------------------------------------
// K3 (MFMA): q^T = Wq * xw^T per window; C-layout store transposes back into
//   d_out q slots.
// ---------------------------------------------------------------------------
__global__ __launch_bounds__(256) void k_q(const float* __restrict__ x,
                                           const short* __restrict__ wqb,
                                           float* __restrict__ qout) {
  const int t = threadIdx.x, lane = t & 63, w = t >> 6;
  const int col = lane & 15, quad = lane >> 4;
  const int n = blockIdx.x;
  const int b = n / CL, l = n - b * CL;
  const int wh = l / 12, ww = l - wh * 12;
  const size_t xwin = (size_t)b * CC * HWSZ + wh * 8 * CWD + ww * 8;

  __shared__ short xq[64][264];
  {
    const int ci = t & 31, ii = t >> 5;
#pragma unroll
    for (int u = 0; u < 8; ++u) {
      const float* ap = x + xwin + (size_t)(ci + 32 * u) * HWSZ + ii * CWD;
      float4 lo = *(const float4*)ap, hi = *(const float4*)(ap + 4);
      float vals[8] = {lo.x, lo.y, lo.z, lo.w, hi.x, hi.y, hi.z, hi.w};
#pragma unroll
      for (int j = 0; j < 8; ++j) xq[ii * 8 + j][ci + 32 * u] = f2b(vals[j]);
    }
  }
  __syncthreads();

  f32x4 acc[4][4] = {};
  for (int kc = 0; kc < 8; ++kc) {
    bf16x8 af[4];
#pragma unroll
    for (int cht = 0; cht < 4; ++cht) {
      s16x8 r = *(const s16x8*)(wqb + (size_t)(w * 64 + cht * 16 + col) * CC + kc * 32 + quad * 8);
      af[cht] = __builtin_bit_cast(bf16x8, r);
    }
#pragma unroll
    for (int qt = 0; qt < 4; ++qt) {
      s16x8 rb = *(const s16x8*)&xq[qt * 16 + col][kc * 32 + quad * 8];
      bf16x8 bfv = __builtin_bit_cast(bf16x8, rb);
#pragma unroll
      for (int cht = 0; cht < 4; ++cht)
        acc[cht][qt] = __builtin_amdgcn_mfma_f32_16x16x32_bf16(af[cht], bfv, acc[cht][qt], 0, 0, 0);
    }
  }

  float* op = qout + (size_t)n * CQ * CC;
#pragma unroll
  for (int qt = 0; qt < 4; ++qt)
#pragma unroll
    for (int cht = 0; cht < 4; ++cht) {
      f32x4 v = acc[cht][qt];
      *(float4*)&op[(qt * 16 + col) * CC + w * 64 + cht * 16 + quad * 4] =
          make_float4(v[0] * QSCALE, v[1] * QSCALE, v[2] * QSCALE, v[3] * QSCALE);
    }
}

// ---------------------------------------------------------------------------
// K4 (MFMA): attention, one wave per (window, head). In-place q -> out.
// ---------------------------------------------------------------------------
__global__ __launch_bounds__(256) void k_attn(const float* __restrict__ kbuf,
                                              const float* __restrict__ vbuf,
                                              float* __restrict__ S) {
  const int t = threadIdx.x;
  const int wv = t >> 6, lane = t & 63;
  const int col = lane & 15, quad = lane >> 4;
  const int task = blockIdx.x * 4 + wv;         // 9216 tasks
  const int n = task >> 3, h = task & 7;
  const int bb = n & 7;

  const float* kh = kbuf + (size_t)(bb * NHEADS + h) * CL * HD;
  const float* vh = vbuf + (size_t)(bb * NHEADS + h) * CL * HD;
  float* Sn = S + (size_t)n * (CQ * CC) + h * HD;

  bf16x8 ka[9];
#pragma unroll
  for (int lt = 0; lt < 9; ++lt) {
    const float* kr = kh + (lt * 16 + col) * HD + quad * 8;
    ka[lt] = pack8(*(const float4*)kr, *(const float4*)(kr + 4));
  }

  s16x4 vt[2][9];
#pragma unroll
  for (int dt = 0; dt < 2; ++dt)
#pragma unroll
    for (int lc = 0; lc < 9; ++lc) {
      s16x4 p;
#pragma unroll
      for (int j = 0; j < 4; ++j)
        p[j] = f2b(vh[(lc * 16 + quad * 4 + j) * HD + dt * 16 + col]);
      vt[dt][lc] = p;
    }

  const f32x4 zero = {0.f, 0.f, 0.f, 0.f};

#pragma unroll
  for (int qt = 0; qt < 4; ++qt) {
    const float* qr = Sn + (size_t)(qt * 16 + col) * CC + quad * 8;
    bf16x8 qb = pack8(*(const float4*)qr, *(const float4*)(qr + 4));

    f32x4 s[9];
#pragma unroll
    for (int lt = 0; lt < 9; ++lt)
      s[lt] = __builtin_amdgcn_mfma_f32_16x16x32_bf16(ka[lt], qb, zero, 0, 0, 0);

    float mx = s[0][0];
#pragma unroll
    for (int lt = 0; lt < 9; ++lt)
#pragma unroll
      for (int r = 0; r < 4; ++r) mx = fmaxf(mx, s[lt][r]);
    mx = fmaxf(mx, __shfl_xor(mx, 16, 64));
    mx = fmaxf(mx, __shfl_xor(mx, 32, 64));

    float sum = 0.f;
    s16x4 pb[9];
#pragma unroll
    for (int lt = 0; lt < 9; ++lt) {
      s16x4 pp;
#pragma unroll
      for (int r = 0; r < 4; ++r) {
        float e = __expf(s[lt][r] - mx);
        sum += e;
        pp[r] = f2b(e);
      }
      pb[lt] = pp;
    }
    sum += __shfl_xor(sum, 16, 64);
    sum += __shfl_xor(sum, 32, 64);
    const float inv = 1.0f / sum;

    f32x4 o0 = zero, o1 = zero;
#pragma unroll
    for (int lc = 0; lc < 9; ++lc) {
      o0 = __builtin_amdgcn_mfma_f32_16x16x16bf16_1k(vt[0][lc], pb[lc], o0, 0, 0, 0);
      o1 = __builtin_amdgcn_mfma_f32_16x16x16bf16_1k(vt[1][lc], pb[lc], o1, 0, 0, 0);
    }

    float* orow = Sn + (size_t)(qt * 16 + col) * CC;
    *(float4*)&orow[quad * 4] =
        make_float4(o0[0] * inv, o0[1] * inv, o0[2] * inv, o0[3] * inv);
    *(float4*)&orow[16 + quad * 4] =
        make_float4(o1[0] * inv, o1[1] * inv, o1[2] * inv, o1[3] * inv);
  }
}

// ---------------------------------------------------------------------------
// K5: depthwise 3x3 RPE (+bias) added into S. One block per (b,c) plane.
// ---------------------------------------------------------------------------
__global__ __launch_bounds__(256) void k_rpe(const float* __restrict__ x,
                                             const float* __restrict__ rw,
                                             const float* __restrict__ rb,
                                             float* __restrict__ S) {
  const int bc = blockIdx.x;
  const int c = bc & 255;
  const int t = threadIdx.x;
  __shared__ float xs[HWSZ];
  const float* xp = x + (size_t)bc * HWSZ;
  float* sp = S + (size_t)bc * HWSZ;
#pragma unroll
  for (int u = 0; u < 36; ++u) xs[t + 256 * u] = xp[t + 256 * u];
  float w9[9];
#pragma unroll
  for (int k = 0; k < 9; ++k) w9[k] = rw[c * 9 + k];
  const float bias = rb[c];
  __syncthreads();
  for (int u = 0; u < 36; ++u) {
    int idx = t + 256 * u;
    int hh = idx / 96, ww = idx - hh * 96;
    float s = bias;
#pragma unroll
    for (int di = 0; di < 3; ++di) {
      int h2 = hh + di - 1;
#pragma unroll
      for (int dj = 0; dj < 3; ++dj) {
        int w2 = ww + dj - 1;
        if ((unsigned)h2 < 96u && (unsigned)w2 < 96u)
          s += xs[h2 * 96 + w2] * w9[di * 3 + dj];
      }
    }
    sp[idx] += s;
  }
}

// ---------------------------------------------------------------------------
// K6 (MFMA): projection, in-place on d_out. Block = 64 rows x 256 cols.
// ---------------------------------------------------------------------------
__global__ __launch_bounds__(256) void k_proj(const short* __restrict__ pjwb,
                                              const float* __restrict__ pjb,
                                              float* __restrict__ S) {
  const int t = threadIdx.x, lane = t & 63, w = t >> 6;
  const int col = lane & 15, quad = lane >> 4;
  const size_t row0 = (size_t)blockIdx.x * 64;

  __shared__ short Sl[64][264];
  const float* Sp = S + row0 * CC;
#pragma unroll
  for (int u = 0; u < 16; ++u) {
    int idx = u * 1024 + t * 4;
    float4 v = *(const float4*)&Sp[idx];
    s16x4 pv;
    pv[0] = f2b(v.x); pv[1] = f2b(v.y); pv[2] = f2b(v.z); pv[3] = f2b(v.w);
    *(s16x4*)&Sl[idx >> 8][idx & 255] = pv;
  }
  __syncthreads();

  f32x4 acc[4][4] = {};
  for (int kc = 0; kc < 8; ++kc) {
    bf16x8 bfr[4];
#pragma unroll
    for (int ot = 0; ot < 4; ++ot) {
      s16x8 r = *(const s16x8*)(pjwb + (size_t)(w * 64 + ot * 16 + col) * CC + kc * 32 + quad * 8);
      bfr[ot] = __builtin_bit_cast(bf16x8, r);
    }
#pragma unroll
    for (int mt = 0; mt < 4; ++mt) {
      s16x8 ra = *(const s16x8*)&Sl[mt * 16 + col][kc * 32 + quad * 8];
      bf16x8 af = __builtin_bit_cast(bf16x8, ra);
#pragma unroll
      for (int ot = 0; ot < 4; ++ot)
        acc[mt][ot] = __builtin_amdgcn_mfma_f32_16x16x32_bf16(af, bfr[ot], acc[mt][ot], 0, 0, 0);
    }
  }

  float bias[4];
#pragma unroll
  for (int ot = 0; ot < 4; ++ot) bias[ot] = pjb[w * 64 + ot * 16 + col];
  float* Sw = S + row0 * CC;
#pragma unroll
  for (int mt = 0; mt < 4; ++mt)
#pragma unroll
    for (int ot = 0; ot < 4; ++ot)
#pragma unroll
      for (int r = 0; r < 4; ++r)
        Sw[(mt * 16 + quad * 4 + r) * CC + w * 64 + ot * 16 + col] = acc[mt][ot][r] + bias[ot];
}

// ---------------------------------------------------------------------------
extern "C" void kernel_launch(void* const* d_in, const int* in_sizes, int n_in,
                              void* d_out, int out_size, void* d_ws, size_t ws_size,
                              hipStream_t stream) {
  const float* x    = (const float*)d_in[0];
  const float* wq   = (const float*)d_in[1];
  const float* wkv  = (const float*)d_in[2];
  const float* pw   = (const float*)d_in[3];
  const float* pbv  = (const float*)d_in[4];
  const float* rw   = (const float*)d_in[5];
  const float* rb   = (const float*)d_in[6];
  const float* pjw  = (const float*)d_in[7];
  const float* pjb  = (const float*)d_in[8];
  float* out = (float*)d_out;
  float* ws  = (float*)d_ws;

  float* pxr  = ws;                               // 1152*256 f
  float* kbuf = pxr + CN * CC;                    // 8*8*144*32 f
  float* vbuf = kbuf + CB * NHEADS * CL * HD;     // 8*8*144*32 f
  short* pw2  = (short*)(vbuf + CB * NHEADS * CL * HD);  // 4194304 sh
  short* wqb  = pw2 + 4194304;                    // 65536 sh
  short* pjwb = wqb + 65536;                      // 65536 sh

  // split-K partials live in d_out (37.7 MB <= 75.5 MB), consumed by k_poolred
  // before k_q overwrites d_out.
  float* part = out;

  k_cvtp   <<<2048, 256, 0, stream>>>(pw, pw2);
  k_cvt    <<<32,   256, 0, stream>>>(wq,  wqb,  8192);
  k_cvt    <<<32,   256, 0, stream>>>(pjw, pjwb, 8192);

  k_pool   <<<dim3(18, 2, NSLICE), 256, 0, stream>>>(x, pw2, part);
  k_poolred<<<288,            256, 0, stream>>>(part, pbv, pxr);
  k_kv     <<<dim3(18, 8),    256, 0, stream>>>(pxr, wkv, kbuf, vbuf);
  k_q      <<<CN,             256, 0, stream>>>(x, wqb, out);
  k_attn   <<<2304,           256, 0, stream>>>(kbuf, vbuf, out);
  k_rpe    <<<CB * CC,        256, 0, stream>>>(x, rw, rb, out);
  k_proj   <<<1152,           256, 0, stream>>>(pjwb, pjb, out);
}